// Round 1
// baseline (20542.598 us; speedup 1.0000x reference)
//
#include <hip/hip_runtime.h>
#include <math.h>

#define T_ 800
#define B_ 32
#define D_ 440
#define H_ 1024
#define L_ 4
#define O_ 2000
#define EPS_ 1e-5f
#define M_ (T_ * B_)   // 25600

#define BM 64
#define BN 64
#define KT 16

// ---------------------------------------------------------------------------
// Fold BN running stats into scale/bias:  y = x*scale + bias
// ---------------------------------------------------------------------------
__global__ void bn_prep(const float* __restrict__ g, const float* __restrict__ b,
                        const float* __restrict__ m, const float* __restrict__ v,
                        float* __restrict__ scale, float* __restrict__ bias, int n)
{
    int i = blockIdx.x * 256 + threadIdx.x;
    if (i < n) {
        float s = g[i] * rsqrtf(v[i] + EPS_);
        scale[i] = s;
        bias[i] = fmaf(-m[i], s, b[i]);
    }
}

// ---------------------------------------------------------------------------
// fp32 NT GEMM: C[m,n] = sum_k A[m,k] * Wt[n,k]   (A:[M,K], Wt:[N,K] row-major)
// mode 0: n<H -> z = sigmoid(bn(val)), n>=H -> c = relu(bn(val))  (split store)
// mode 1: logits -> bn affine -> fout
// ---------------------------------------------------------------------------
__global__ __launch_bounds__(256) void gemm_fused(
    const float* __restrict__ A, const float* __restrict__ Wt,
    int M, int N, int K, int mode,
    float* __restrict__ zout, float* __restrict__ cout,
    const float* __restrict__ zscale, const float* __restrict__ zbias,
    const float* __restrict__ cscale, const float* __restrict__ cbias,
    float* __restrict__ fout,
    const float* __restrict__ fscale, const float* __restrict__ fbias)
{
    __shared__ float As[BM][KT + 4];   // +4 keeps float4 alignment, <=2-way bank alias (free)
    __shared__ float Bs[BN][KT + 4];

    const int tid = threadIdx.x;
    const int m0 = blockIdx.y * BM;
    const int n0 = blockIdx.x * BN;
    const int tx = tid & 15, ty = tid >> 4;
    const int lrow = tid >> 2;
    const int lk = (tid & 3) << 2;

    float acc[4][4];
    #pragma unroll
    for (int i = 0; i < 4; i++)
        #pragma unroll
        for (int j = 0; j < 4; j++) acc[i][j] = 0.f;

    for (int k0 = 0; k0 < K; k0 += KT) {
        const int gk = k0 + lk;
        // ---- stage A tile ----
        {
            int gm = m0 + lrow;
            float4 v = make_float4(0.f, 0.f, 0.f, 0.f);
            if (gm < M && gk < K) {
                if (gk + 4 <= K) {
                    v = *(const float4*)(A + (size_t)gm * K + gk);
                } else {
                    const float* p = A + (size_t)gm * K;
                    float tv[4] = {0.f, 0.f, 0.f, 0.f};
                    #pragma unroll
                    for (int j = 0; j < 4; j++) if (gk + j < K) tv[j] = p[gk + j];
                    v = make_float4(tv[0], tv[1], tv[2], tv[3]);
                }
            }
            *(float4*)(&As[lrow][lk]) = v;
        }
        // ---- stage B tile ----
        {
            int gn = n0 + lrow;
            float4 v = make_float4(0.f, 0.f, 0.f, 0.f);
            if (gn < N && gk < K) {
                if (gk + 4 <= K) {
                    v = *(const float4*)(Wt + (size_t)gn * K + gk);
                } else {
                    const float* p = Wt + (size_t)gn * K;
                    float tv[4] = {0.f, 0.f, 0.f, 0.f};
                    #pragma unroll
                    for (int j = 0; j < 4; j++) if (gk + j < K) tv[j] = p[gk + j];
                    v = make_float4(tv[0], tv[1], tv[2], tv[3]);
                }
            }
            *(float4*)(&Bs[lrow][lk]) = v;
        }
        __syncthreads();

        #pragma unroll
        for (int kk = 0; kk < KT; kk += 4) {
            float4 a[4], b[4];
            #pragma unroll
            for (int i = 0; i < 4; i++) a[i] = *(const float4*)(&As[ty * 4 + i][kk]);
            #pragma unroll
            for (int j = 0; j < 4; j++) b[j] = *(const float4*)(&Bs[tx * 4 + j][kk]);
            #pragma unroll
            for (int i = 0; i < 4; i++)
                #pragma unroll
                for (int j = 0; j < 4; j++) {
                    acc[i][j] = fmaf(a[i].x, b[j].x, acc[i][j]);
                    acc[i][j] = fmaf(a[i].y, b[j].y, acc[i][j]);
                    acc[i][j] = fmaf(a[i].z, b[j].z, acc[i][j]);
                    acc[i][j] = fmaf(a[i].w, b[j].w, acc[i][j]);
                }
        }
        __syncthreads();
    }

    const int mbase = m0 + ty * 4;
    const int nbase = n0 + tx * 4;
    if (mode == 0) {
        const bool isz = (n0 < H_);   // BN=64 divides H: whole tile is one branch
        #pragma unroll
        for (int i = 0; i < 4; i++) {
            int m = mbase + i;
            if (m >= M) continue;
            #pragma unroll
            for (int j = 0; j < 4; j++) {
                int n = nbase + j;
                float val = acc[i][j];
                if (isz) {
                    float bnv = fmaf(val, zscale[n], zbias[n]);
                    zout[(size_t)m * H_ + n] = 1.f / (1.f + expf(-bnv));
                } else {
                    int nn = n - H_;
                    float bnv = fmaf(val, cscale[nn], cbias[nn]);
                    cout[(size_t)m * H_ + nn] = fmaxf(bnv, 0.f);
                }
            }
        }
    } else {
        #pragma unroll
        for (int i = 0; i < 4; i++) {
            int m = mbase + i;
            if (m >= M) continue;
            #pragma unroll
            for (int j = 0; j < 4; j++) {
                int n = nbase + j;
                if (n < N)
                    fout[(size_t)m * N + n] = fmaf(acc[i][j], fscale[n], fbias[n]);
            }
        }
    }
}

// ---------------------------------------------------------------------------
// Sequential scan over T: h_t = (1-z)*c + z*h = c + z*(h-c).  One thread per (b,h).
// ---------------------------------------------------------------------------
__global__ __launch_bounds__(256) void scan_kernel(
    const float* __restrict__ z, const float* __restrict__ c, float* __restrict__ x)
{
    const int idx = blockIdx.x * 256 + threadIdx.x;   // < B_*H_
    float h = 0.f;
    size_t off = idx;
    #pragma unroll 8
    for (int t = 0; t < T_; ++t) {
        float zt = z[off];
        float ct = c[off];
        h = fmaf(zt, h - ct, ct);
        x[off] = h;
        off += (size_t)(B_ * H_);
    }
}

// ---------------------------------------------------------------------------
// Row-wise log_softmax over O=2000, in place.  One block (256 thr) per row.
// ---------------------------------------------------------------------------
__global__ __launch_bounds__(256) void logsoftmax_kernel(float* __restrict__ out)
{
    const int row = blockIdx.x;
    float* p = out + (size_t)row * O_;
    const int tid = threadIdx.x;

    float v[8];
    float mx = -1e30f;
    #pragma unroll
    for (int j = 0; j < 8; j++) {
        int col = tid + j * 256;
        v[j] = (col < O_) ? p[col] : -1e30f;
        mx = fmaxf(mx, v[j]);
    }
    #pragma unroll
    for (int o = 32; o > 0; o >>= 1) mx = fmaxf(mx, __shfl_down(mx, o));
    __shared__ float smax[4];
    __shared__ float ssum[4];
    const int lane = tid & 63, wid = tid >> 6;
    if (lane == 0) smax[wid] = mx;
    __syncthreads();
    mx = fmaxf(fmaxf(smax[0], smax[1]), fmaxf(smax[2], smax[3]));

    float s = 0.f;
    #pragma unroll
    for (int j = 0; j < 8; j++) {
        int col = tid + j * 256;
        if (col < O_) s += expf(v[j] - mx);
    }
    #pragma unroll
    for (int o = 32; o > 0; o >>= 1) s += __shfl_down(s, o);
    if (lane == 0) ssum[wid] = s;
    __syncthreads();
    s = ssum[0] + ssum[1] + ssum[2] + ssum[3];
    const float lse = mx + logf(s);

    #pragma unroll
    for (int j = 0; j < 8; j++) {
        int col = tid + j * 256;
        if (col < O_) p[col] = v[j] - lse;
    }
}

// ---------------------------------------------------------------------------
extern "C" void kernel_launch(void* const* d_in, const int* in_sizes, int n_in,
                              void* d_out, int out_size, void* d_ws, size_t ws_size,
                              hipStream_t stream)
{
    (void)in_sizes; (void)n_in; (void)out_size; (void)ws_size;

    const float* xs    = (const float*)d_in[0];
    const float* w0    = (const float*)d_in[1];
    const float* wr    = (const float*)d_in[2];
    const float* bnz_g = (const float*)d_in[3];
    const float* bnz_b = (const float*)d_in[4];
    const float* bnz_m = (const float*)d_in[5];
    const float* bnz_v = (const float*)d_in[6];
    const float* bnc_g = (const float*)d_in[7];
    const float* bnc_b = (const float*)d_in[8];
    const float* bnc_m = (const float*)d_in[9];
    const float* bnc_v = (const float*)d_in[10];
    const float* wf    = (const float*)d_in[11];
    const float* bnf_g = (const float*)d_in[12];
    const float* bnf_b = (const float*)d_in[13];
    const float* bnf_m = (const float*)d_in[14];
    const float* bnf_v = (const float*)d_in[15];
    float* out = (float*)d_out;

    float* ws = (float*)d_ws;
    const size_t MH = (size_t)M_ * H_;
    float* xbuf = ws;                 // [M, H]
    float* zbuf = xbuf + MH;          // [M, H]
    float* cbuf = zbuf + MH;          // [M, H]
    float* zs = cbuf + MH;            // [L, H]
    float* zb = zs + L_ * H_;
    float* cs = zb + L_ * H_;
    float* cb = cs + L_ * H_;
    float* fs = cb + L_ * H_;         // [O]
    float* fb = fs + O_;

    bn_prep<<<(L_ * H_ + 255) / 256, 256, 0, stream>>>(bnz_g, bnz_b, bnz_m, bnz_v, zs, zb, L_ * H_);
    bn_prep<<<(L_ * H_ + 255) / 256, 256, 0, stream>>>(bnc_g, bnc_b, bnc_m, bnc_v, cs, cb, L_ * H_);
    bn_prep<<<(O_ + 255) / 256, 256, 0, stream>>>(bnf_g, bnf_b, bnf_m, bnf_v, fs, fb, O_);

    dim3 blk(256);
    for (int layer = 0; layer < L_; ++layer) {
        const float* Ain = (layer == 0) ? xs : xbuf;
        const float* W   = (layer == 0) ? w0 : (wr + (size_t)(layer - 1) * (2 * H_) * H_);
        const int K      = (layer == 0) ? D_ : H_;
        dim3 grid((2 * H_) / BN, M_ / BM);
        gemm_fused<<<grid, blk, 0, stream>>>(Ain, W, M_, 2 * H_, K, 0,
            zbuf, cbuf,
            zs + layer * H_, zb + layer * H_, cs + layer * H_, cb + layer * H_,
            nullptr, nullptr, nullptr);
        scan_kernel<<<(B_ * H_) / 256, blk, 0, stream>>>(zbuf, cbuf, xbuf);
    }

    dim3 gridf((O_ + BN - 1) / BN, M_ / BM);
    gemm_fused<<<gridf, blk, 0, stream>>>(xbuf, wf, M_, O_, H_, 1,
        nullptr, nullptr, nullptr, nullptr, nullptr, nullptr,
        out, fs, fb);

    logsoftmax_kernel<<<M_, blk, 0, stream>>>(out);
}

// Round 2
// 1585.773 us; speedup vs baseline: 12.9543x; 12.9543x over previous
//
#include <hip/hip_runtime.h>
#include <math.h>
#include <stdint.h>

#define T_ 800
#define B_ 32
#define D_ 440
#define DP_ 448      // D padded to mult of 32 (and 16B rows)
#define H_ 1024
#define L_ 4
#define O_ 2000
#define OP_ 2048     // O rows padded to mult of 128
#define EPS_ 1e-5f
#define M_ (T_ * B_)   // 25600

#define BM 128
#define BN 128
#define BK 32

typedef __attribute__((ext_vector_type(8))) short bf16x8;
typedef __attribute__((ext_vector_type(4))) float f32x4;

__device__ inline float b2f(unsigned short u) {
    union { unsigned int i; float f; } v; v.i = ((unsigned int)u) << 16; return v.f;
}
__device__ inline unsigned short f2b(float f) {   // RNE bf16 (finite values only)
    unsigned int x = __float_as_uint(f);
    return (unsigned short)((x + 0x7FFFu + ((x >> 16) & 1u)) >> 16);
}

// ---------------------------------------------------------------------------
// BN fold: y = x*scale + bias
// ---------------------------------------------------------------------------
__global__ void bn_prep(const float* __restrict__ g, const float* __restrict__ b,
                        const float* __restrict__ m, const float* __restrict__ v,
                        float* __restrict__ scale, float* __restrict__ bias, int n)
{
    int i = blockIdx.x * 256 + threadIdx.x;
    if (i < n) {
        float s = g[i] * rsqrtf(v[i] + EPS_);
        scale[i] = s;
        bias[i] = fmaf(-m[i], s, b[i]);
    }
}

// ---------------------------------------------------------------------------
// fp32 [Rs x Cs] -> bf16 [.. x Cd] with zero padding (rows beyond Rs, cols >= Cs)
// ---------------------------------------------------------------------------
__global__ void cvt_pad(const float* __restrict__ src, unsigned short* __restrict__ dst,
                        int Rs, int Cs, int Cd, int total)
{
    int i = blockIdx.x * 256 + threadIdx.x;
    if (i >= total) return;
    int r = i / Cd, c = i - r * Cd;
    float v = (r < Rs && c < Cs) ? src[(size_t)r * Cs + c] : 0.f;
    dst[i] = f2b(v);
}

// ---------------------------------------------------------------------------
// bf16 NT GEMM, m97 structure: C[m,n] = sum_k A[m,k]*Wt[n,k]
// A:[M x K] bf16 row-major (K mult of 32, rows 16B aligned)
// Wt:[Npad x K] bf16 row-major, Npad = gridDim.x*128
// mode 0: n<H -> z=sigmoid(bn), n>=H -> c=relu(bn); bf16 stores to zout/cout [M x H]
// mode 1: fout[m,n] = bn affine, fp32, guard n<O_
// ---------------------------------------------------------------------------
__global__ __launch_bounds__(256) void gemm_bf16(
    const unsigned short* __restrict__ A, const unsigned short* __restrict__ Wt,
    int K, int mode,
    unsigned short* __restrict__ zout, unsigned short* __restrict__ cout,
    const float* __restrict__ zscale, const float* __restrict__ zbias,
    const float* __restrict__ cscale, const float* __restrict__ cbias,
    float* __restrict__ fout,
    const float* __restrict__ fscale, const float* __restrict__ fbias)
{
    __shared__ unsigned short As[BM * BK];   // 8 KB
    __shared__ unsigned short Bs[BN * BK];   // 8 KB

    const int tid = threadIdx.x;
    const int lane = tid & 63;
    const int wid = tid >> 6;            // 0..3
    const int wm = wid >> 1, wn = wid & 1;
    const int m0 = blockIdx.y * BM;
    const int n0 = blockIdx.x * BN;

    // staging: each global_load_lds covers 16 rows x 32 cols (1 KB); lane -> (row=lane>>2, 16B chunk=lane&3)
    const int srow = lane >> 2;
    const int scol = (lane & 3) * 8;     // element offset

    f32x4 acc[4][4];
    #pragma unroll
    for (int i = 0; i < 4; i++)
        #pragma unroll
        for (int j = 0; j < 4; j++)
            acc[i][j] = (f32x4){0.f, 0.f, 0.f, 0.f};

    const int fr = lane & 15;            // fragment row (m or n)
    const int fk = (lane >> 4) * 8;      // fragment k offset

    for (int k0 = 0; k0 < K; k0 += BK) {
        #pragma unroll
        for (int i = 0; i < 2; i++) {
            const int chunk = wid * 2 + i;                 // 0..7, wave-uniform
            const unsigned short* g = A + (size_t)(m0 + chunk * 16 + srow) * K + k0 + scol;
            __builtin_amdgcn_global_load_lds(
                (const __attribute__((address_space(1))) unsigned int*)g,
                (__attribute__((address_space(3))) unsigned int*)(As + chunk * 16 * BK),
                16, 0, 0);
        }
        #pragma unroll
        for (int i = 0; i < 2; i++) {
            const int chunk = wid * 2 + i;
            const unsigned short* g = Wt + (size_t)(n0 + chunk * 16 + srow) * K + k0 + scol;
            __builtin_amdgcn_global_load_lds(
                (const __attribute__((address_space(1))) unsigned int*)g,
                (__attribute__((address_space(3))) unsigned int*)(Bs + chunk * 16 * BK),
                16, 0, 0);
        }
        __syncthreads();   // compiler emits s_waitcnt vmcnt(0) before s_barrier

        bf16x8 af[4], bfr[4];
        #pragma unroll
        for (int t = 0; t < 4; t++) {
            af[t]  = *(const bf16x8*)(As + (wm * 64 + t * 16 + fr) * BK + fk);
            bfr[t] = *(const bf16x8*)(Bs + (wn * 64 + t * 16 + fr) * BK + fk);
        }
        #pragma unroll
        for (int mi = 0; mi < 4; mi++)
            #pragma unroll
            for (int ni = 0; ni < 4; ni++)
                acc[mi][ni] = __builtin_amdgcn_mfma_f32_16x16x32_bf16(af[mi], bfr[ni], acc[mi][ni], 0, 0, 0);
        __syncthreads();
    }

    // epilogue: D element (m,n): m = rbase + mi*16 + r, n = cbase + ni*16
    const int cbase = n0 + wn * 64 + (lane & 15);
    const int rbase = m0 + wm * 64 + (lane >> 4) * 4;
    if (mode == 0) {
        const bool isz = (n0 < H_);      // BN=128 divides H: whole block one branch
        const float* sc = isz ? zscale : cscale;
        const float* bi = isz ? zbias : cbias;
        unsigned short* dst = isz ? zout : cout;
        #pragma unroll
        for (int ni = 0; ni < 4; ni++) {
            const int n = cbase + ni * 16;
            const int np = isz ? n : n - H_;
            const float s = sc[np], b = bi[np];
            #pragma unroll
            for (int mi = 0; mi < 4; mi++)
                #pragma unroll
                for (int r = 0; r < 4; r++) {
                    const int m = rbase + mi * 16 + r;
                    float v = fmaf(acc[mi][ni][r], s, b);
                    v = isz ? (1.f / (1.f + expf(-v))) : fmaxf(v, 0.f);
                    dst[(size_t)m * H_ + np] = f2b(v);
                }
        }
    } else {
        #pragma unroll
        for (int ni = 0; ni < 4; ni++) {
            const int n = cbase + ni * 16;
            if (n < O_) {
                const float s = fscale[n], b = fbias[n];
                #pragma unroll
                for (int mi = 0; mi < 4; mi++)
                    #pragma unroll
                    for (int r = 0; r < 4; r++) {
                        const int m = rbase + mi * 16 + r;
                        fout[(size_t)m * O_ + n] = fmaf(acc[mi][ni][r], s, b);
                    }
            }
        }
    }
}

// ---------------------------------------------------------------------------
// scan over T: h = c + z*(h-c); bf16 in, bf16 out, fp32 state
// ---------------------------------------------------------------------------
__global__ __launch_bounds__(256) void scan_kernel(
    const unsigned short* __restrict__ z, const unsigned short* __restrict__ c,
    unsigned short* __restrict__ x)
{
    const int idx = blockIdx.x * 256 + threadIdx.x;   // < B_*H_
    float h = 0.f;
    size_t off = idx;
    #pragma unroll 8
    for (int t = 0; t < T_; ++t) {
        float zt = b2f(z[off]);
        float ct = b2f(c[off]);
        h = fmaf(zt, h - ct, ct);
        x[off] = f2b(h);
        off += (size_t)(B_ * H_);
    }
}

// ---------------------------------------------------------------------------
// row-wise log_softmax over O=2000, in place
// ---------------------------------------------------------------------------
__global__ __launch_bounds__(256) void logsoftmax_kernel(float* __restrict__ out)
{
    const int row = blockIdx.x;
    float* p = out + (size_t)row * O_;
    const int tid = threadIdx.x;

    float v[8];
    float mx = -1e30f;
    #pragma unroll
    for (int j = 0; j < 8; j++) {
        int col = tid + j * 256;
        v[j] = (col < O_) ? p[col] : -1e30f;
        mx = fmaxf(mx, v[j]);
    }
    #pragma unroll
    for (int o = 32; o > 0; o >>= 1) mx = fmaxf(mx, __shfl_down(mx, o));
    __shared__ float smax[4];
    __shared__ float ssum[4];
    const int lane = tid & 63, wid = tid >> 6;
    if (lane == 0) smax[wid] = mx;
    __syncthreads();
    mx = fmaxf(fmaxf(smax[0], smax[1]), fmaxf(smax[2], smax[3]));

    float s = 0.f;
    #pragma unroll
    for (int j = 0; j < 8; j++) {
        int col = tid + j * 256;
        if (col < O_) s += expf(v[j] - mx);
    }
    #pragma unroll
    for (int o = 32; o > 0; o >>= 1) s += __shfl_down(s, o);
    if (lane == 0) ssum[wid] = s;
    __syncthreads();
    s = ssum[0] + ssum[1] + ssum[2] + ssum[3];
    const float lse = mx + logf(s);

    #pragma unroll
    for (int j = 0; j < 8; j++) {
        int col = tid + j * 256;
        if (col < O_) p[col] = v[j] - lse;
    }
}

// ---------------------------------------------------------------------------
extern "C" void kernel_launch(void* const* d_in, const int* in_sizes, int n_in,
                              void* d_out, int out_size, void* d_ws, size_t ws_size,
                              hipStream_t stream)
{
    (void)in_sizes; (void)n_in; (void)out_size; (void)ws_size;

    const float* xs    = (const float*)d_in[0];
    const float* w0    = (const float*)d_in[1];
    const float* wr    = (const float*)d_in[2];
    const float* bnz_g = (const float*)d_in[3];
    const float* bnz_b = (const float*)d_in[4];
    const float* bnz_m = (const float*)d_in[5];
    const float* bnz_v = (const float*)d_in[6];
    const float* bnc_g = (const float*)d_in[7];
    const float* bnc_b = (const float*)d_in[8];
    const float* bnc_m = (const float*)d_in[9];
    const float* bnc_v = (const float*)d_in[10];
    const float* wf    = (const float*)d_in[11];
    const float* bnf_g = (const float*)d_in[12];
    const float* bnf_b = (const float*)d_in[13];
    const float* bnf_m = (const float*)d_in[14];
    const float* bnf_v = (const float*)d_in[15];
    float* out = (float*)d_out;

    // workspace layout (bf16 buffers first, then fp32 params)
    unsigned short* p = (unsigned short*)d_ws;
    unsigned short* xbuf  = p;  p += (size_t)M_ * H_;      // scan output / GEMM input
    unsigned short* x0buf = p;  p += (size_t)M_ * DP_;     // xs padded bf16
    unsigned short* zbuf  = p;  p += (size_t)M_ * H_;
    unsigned short* cbuf  = p;  p += (size_t)M_ * H_;
    unsigned short* w0p   = p;  p += (size_t)(2 * H_) * DP_;
    unsigned short* wrp   = p;  p += (size_t)(L_ - 1) * (2 * H_) * H_;
    unsigned short* wfp   = p;  p += (size_t)OP_ * H_;
    float* fp = (float*)p;
    float* zs = fp;  fp += L_ * H_;
    float* zb = fp;  fp += L_ * H_;
    float* cs = fp;  fp += L_ * H_;
    float* cb = fp;  fp += L_ * H_;
    float* fs = fp;  fp += O_;
    float* fb = fp;

    dim3 blk(256);
    bn_prep<<<(L_ * H_ + 255) / 256, blk, 0, stream>>>(bnz_g, bnz_b, bnz_m, bnz_v, zs, zb, L_ * H_);
    bn_prep<<<(L_ * H_ + 255) / 256, blk, 0, stream>>>(bnc_g, bnc_b, bnc_m, bnc_v, cs, cb, L_ * H_);
    bn_prep<<<(O_ + 255) / 256, blk, 0, stream>>>(bnf_g, bnf_b, bnf_m, bnf_v, fs, fb, O_);

    {   // bf16 conversions with padding
        int t0 = M_ * DP_;
        cvt_pad<<<(t0 + 255) / 256, blk, 0, stream>>>(xs, x0buf, M_, D_, DP_, t0);
        int t1 = 2 * H_ * DP_;
        cvt_pad<<<(t1 + 255) / 256, blk, 0, stream>>>(w0, w0p, 2 * H_, D_, DP_, t1);
        int t2 = (L_ - 1) * 2 * H_ * H_;
        cvt_pad<<<(t2 + 255) / 256, blk, 0, stream>>>(wr, wrp, (L_ - 1) * 2 * H_, H_, H_, t2);
        int t3 = OP_ * H_;
        cvt_pad<<<(t3 + 255) / 256, blk, 0, stream>>>(wf, wfp, O_, H_, H_, t3);
    }

    for (int layer = 0; layer < L_; ++layer) {
        const unsigned short* Ain = (layer == 0) ? x0buf : xbuf;
        const unsigned short* W   = (layer == 0) ? w0p : (wrp + (size_t)(layer - 1) * (2 * H_) * H_);
        const int K               = (layer == 0) ? DP_ : H_;
        dim3 grid((2 * H_) / BN, M_ / BM);
        gemm_bf16<<<grid, blk, 0, stream>>>(Ain, W, K, 0,
            zbuf, cbuf,
            zs + layer * H_, zb + layer * H_, cs + layer * H_, cb + layer * H_,
            nullptr, nullptr, nullptr);
        scan_kernel<<<(B_ * H_) / 256, blk, 0, stream>>>(zbuf, cbuf, xbuf);
    }

    dim3 gridf(OP_ / BN, M_ / BM);
    gemm_bf16<<<gridf, blk, 0, stream>>>(xbuf, wfp, H_, 1,
        nullptr, nullptr, nullptr, nullptr, nullptr, nullptr,
        out, fs, fb);

    logsoftmax_kernel<<<M_, blk, 0, stream>>>(out);
}

// Round 3
// 1328.498 us; speedup vs baseline: 15.4630x; 1.1937x over previous
//
#include <hip/hip_runtime.h>
#include <math.h>
#include <stdint.h>

#define T_ 800
#define B_ 32
#define D_ 440
#define DP_ 448      // D padded to mult of 32
#define H_ 1024
#define L_ 4
#define O_ 2000
#define OP_ 2048     // O padded to mult of 128
#define EPS_ 1e-5f
#define M_ (T_ * B_)   // 25600
#define NC_ 8
#define TC_ (T_ / NC_) // 100

#define BM 128
#define BN 128
#define BK 32

typedef __attribute__((ext_vector_type(8))) short bf16x8;
typedef __attribute__((ext_vector_type(4))) float f32x4;

__device__ inline float b2f(unsigned short u) {
    union { unsigned int i; float f; } v; v.i = ((unsigned int)u) << 16; return v.f;
}
__device__ inline unsigned short f2b(float f) {   // RNE bf16 (finite only)
    unsigned int x = __float_as_uint(f);
    return (unsigned short)((x + 0x7FFFu + ((x >> 16) & 1u)) >> 16);
}

// ---------------------------------------------------------------------------
// BN fold with dst padding: y = x*scale + bias; i >= nsrc -> 0
// ---------------------------------------------------------------------------
__global__ void bn_prep(const float* __restrict__ g, const float* __restrict__ b,
                        const float* __restrict__ m, const float* __restrict__ v,
                        float* __restrict__ scale, float* __restrict__ bias,
                        int nsrc, int ndst)
{
    int i = blockIdx.x * 256 + threadIdx.x;
    if (i >= ndst) return;
    if (i < nsrc) {
        float s = g[i] * rsqrtf(v[i] + EPS_);
        scale[i] = s;
        bias[i] = fmaf(-m[i], s, b[i]);
    } else {
        scale[i] = 0.f;
        bias[i] = 0.f;
    }
}

// ---------------------------------------------------------------------------
// fp32 [Rs x Cs] -> bf16 [.. x Cd] with zero padding
// ---------------------------------------------------------------------------
__global__ void cvt_pad(const float* __restrict__ src, unsigned short* __restrict__ dst,
                        int Rs, int Cs, int Cd, int total)
{
    int i = blockIdx.x * 256 + threadIdx.x;
    if (i >= total) return;
    int r = i / Cd, c = i - r * Cd;
    float v = (r < Rs && c < Cs) ? src[(size_t)r * Cs + c] : 0.f;
    dst[i] = f2b(v);
}

// ---------------------------------------------------------------------------
// bf16 NT GEMM, m97 structure, column-interleaved B tiles.
// B LDS slot s holds global row  n0 + (s>>6)*64 + (s&15)*4 + ((s>>4)&3)
// => MFMA tile ni within a wave-half covers global cols {base + 4k + ni},
//    so one lane's 4 ni-values are 4 CONSECUTIVE columns -> 8B packed stores.
// mode 0: n<H -> z=sigmoid(bn), else c=relu(bn); bf16 [M x H]
// mode 1: logits bf16 [M x OP_], bn affine only
// ---------------------------------------------------------------------------
__global__ __launch_bounds__(256) void gemm_bf16(
    const unsigned short* __restrict__ A, const unsigned short* __restrict__ Wt,
    int K, int mode,
    unsigned short* __restrict__ zout, unsigned short* __restrict__ cout,
    const float* __restrict__ zscale, const float* __restrict__ zbias,
    const float* __restrict__ cscale, const float* __restrict__ cbias,
    unsigned short* __restrict__ fout,
    const float* __restrict__ fscale, const float* __restrict__ fbias)
{
    __shared__ unsigned short As[BM * BK];   // 8 KB
    __shared__ unsigned short Bs[BN * BK];   // 8 KB

    const int tid = threadIdx.x;
    const int lane = tid & 63;
    const int wid = tid >> 6;            // 0..3
    const int wm = wid >> 1, wn = wid & 1;
    const int m0 = blockIdx.y * BM;
    const int n0 = blockIdx.x * BN;

    const int srow = lane >> 2;
    const int scol = (lane & 3) * 8;     // element offset within row

    // staging row pointers (advance by BK per iter via k0)
    const int ca0 = wid * 2, ca1 = wid * 2 + 1;
    const unsigned short* aR0 = A + (size_t)(m0 + ca0 * 16 + srow) * K + scol;
    const unsigned short* aR1 = A + (size_t)(m0 + ca1 * 16 + srow) * K + scol;
    const int gn0 = n0 + ((ca0 >> 2) << 6) + srow * 4 + (ca0 & 3);
    const int gn1 = n0 + ((ca1 >> 2) << 6) + srow * 4 + (ca1 & 3);
    const unsigned short* bR0 = Wt + (size_t)gn0 * K + scol;
    const unsigned short* bR1 = Wt + (size_t)gn1 * K + scol;
    unsigned short* lA0 = As + ca0 * 16 * BK;
    unsigned short* lA1 = As + ca1 * 16 * BK;
    unsigned short* lB0 = Bs + ca0 * 16 * BK;
    unsigned short* lB1 = Bs + ca1 * 16 * BK;

    f32x4 acc[4][4];
    #pragma unroll
    for (int i = 0; i < 4; i++)
        #pragma unroll
        for (int j = 0; j < 4; j++)
            acc[i][j] = (f32x4){0.f, 0.f, 0.f, 0.f};

    const int fr = lane & 15;            // fragment row
    const int fk = (lane >> 4) * 8;      // fragment k offset

    for (int k0 = 0; k0 < K; k0 += BK) {
        __builtin_amdgcn_global_load_lds(
            (const __attribute__((address_space(1))) unsigned int*)(aR0 + k0),
            (__attribute__((address_space(3))) unsigned int*)lA0, 16, 0, 0);
        __builtin_amdgcn_global_load_lds(
            (const __attribute__((address_space(1))) unsigned int*)(aR1 + k0),
            (__attribute__((address_space(3))) unsigned int*)lA1, 16, 0, 0);
        __builtin_amdgcn_global_load_lds(
            (const __attribute__((address_space(1))) unsigned int*)(bR0 + k0),
            (__attribute__((address_space(3))) unsigned int*)lB0, 16, 0, 0);
        __builtin_amdgcn_global_load_lds(
            (const __attribute__((address_space(1))) unsigned int*)(bR1 + k0),
            (__attribute__((address_space(3))) unsigned int*)lB1, 16, 0, 0);
        __syncthreads();

        bf16x8 af[4], bfr[4];
        #pragma unroll
        for (int t = 0; t < 4; t++) {
            af[t]  = *(const bf16x8*)(As + (wm * 64 + t * 16 + fr) * BK + fk);
            bfr[t] = *(const bf16x8*)(Bs + (wn * 64 + t * 16 + fr) * BK + fk);
        }
        #pragma unroll
        for (int mi = 0; mi < 4; mi++)
            #pragma unroll
            for (int ni = 0; ni < 4; ni++)
                acc[mi][ni] = __builtin_amdgcn_mfma_f32_16x16x32_bf16(af[mi], bfr[ni], acc[mi][ni], 0, 0, 0);
        __syncthreads();
    }

    // ---- epilogue ----
    const int q = lane >> 4;
    const int colb = n0 + wn * 64 + (lane & 15) * 4;   // global col of ni=0 (4 consecutive)
    const int rbase = m0 + wm * 64 + q * 4;

    if (mode == 0) {
        const bool isz = (n0 < H_);
        const float* sc = isz ? zscale : cscale;
        const float* bi = isz ? zbias : cbias;
        unsigned short* dst = isz ? zout : cout;
        const int npb = isz ? colb : colb - H_;
        const float4 s4 = *(const float4*)(sc + npb);
        const float4 b4 = *(const float4*)(bi + npb);
        #pragma unroll
        for (int mi = 0; mi < 4; mi++)
            #pragma unroll
            for (int r = 0; r < 4; r++) {
                const int m = rbase + mi * 16 + r;
                float v0 = fmaf(acc[mi][0][r], s4.x, b4.x);
                float v1 = fmaf(acc[mi][1][r], s4.y, b4.y);
                float v2 = fmaf(acc[mi][2][r], s4.z, b4.z);
                float v3 = fmaf(acc[mi][3][r], s4.w, b4.w);
                if (isz) {
                    v0 = __builtin_amdgcn_rcpf(1.f + __expf(-v0));
                    v1 = __builtin_amdgcn_rcpf(1.f + __expf(-v1));
                    v2 = __builtin_amdgcn_rcpf(1.f + __expf(-v2));
                    v3 = __builtin_amdgcn_rcpf(1.f + __expf(-v3));
                } else {
                    v0 = fmaxf(v0, 0.f); v1 = fmaxf(v1, 0.f);
                    v2 = fmaxf(v2, 0.f); v3 = fmaxf(v3, 0.f);
                }
                ushort4 pk = make_ushort4(f2b(v0), f2b(v1), f2b(v2), f2b(v3));
                *(ushort4*)(dst + (size_t)m * H_ + npb) = pk;
            }
    } else {
        const float4 s4 = *(const float4*)(fscale + colb);
        const float4 b4 = *(const float4*)(fbias + colb);
        #pragma unroll
        for (int mi = 0; mi < 4; mi++)
            #pragma unroll
            for (int r = 0; r < 4; r++) {
                const int m = rbase + mi * 16 + r;
                ushort4 pk = make_ushort4(
                    f2b(fmaf(acc[mi][0][r], s4.x, b4.x)),
                    f2b(fmaf(acc[mi][1][r], s4.y, b4.y)),
                    f2b(fmaf(acc[mi][2][r], s4.z, b4.z)),
                    f2b(fmaf(acc[mi][3][r], s4.w, b4.w)));
                *(ushort4*)(fout + (size_t)m * OP_ + colb) = pk;
            }
    }
}

// ---------------------------------------------------------------------------
// Scan pass 1: per-chunk (H0, P) with h_in = 0.  h' = c + z*(h-c); P = prod z.
// ---------------------------------------------------------------------------
__global__ __launch_bounds__(256) void scan_pass1(
    const unsigned short* __restrict__ z, const unsigned short* __restrict__ c,
    float* __restrict__ H0, float* __restrict__ P)
{
    const int k = blockIdx.y;
    const int idx = blockIdx.x * 256 + threadIdx.x;   // < B_*H_
    float h = 0.f, p = 1.f;
    size_t off = (size_t)k * TC_ * (B_ * H_) + idx;
    #pragma unroll 4
    for (int t = 0; t < TC_; ++t) {
        float zt = b2f(z[off]);
        float ct = b2f(c[off]);
        h = fmaf(zt, h - ct, ct);
        p *= zt;
        off += (size_t)(B_ * H_);
    }
    H0[(size_t)k * (B_ * H_) + idx] = h;
    P[(size_t)k * (B_ * H_) + idx] = p;
}

// ---------------------------------------------------------------------------
// Scan pass 2: fold chunk states (exact affine composition), rerun chunk, write x.
// ---------------------------------------------------------------------------
__global__ __launch_bounds__(256) void scan_pass2(
    const unsigned short* __restrict__ z, const unsigned short* __restrict__ c,
    const float* __restrict__ H0, const float* __restrict__ P,
    unsigned short* __restrict__ x)
{
    const int k = blockIdx.y;
    const int idx = blockIdx.x * 256 + threadIdx.x;
    float h = 0.f;
    for (int j = 0; j < k; ++j)   // k is block-uniform: no divergence
        h = fmaf(P[(size_t)j * (B_ * H_) + idx], h, H0[(size_t)j * (B_ * H_) + idx]);
    size_t off = (size_t)k * TC_ * (B_ * H_) + idx;
    #pragma unroll 4
    for (int t = 0; t < TC_; ++t) {
        float zt = b2f(z[off]);
        float ct = b2f(c[off]);
        h = fmaf(zt, h - ct, ct);
        x[off] = f2b(h);
        off += (size_t)(B_ * H_);
    }
}

// ---------------------------------------------------------------------------
// row-wise log_softmax: bf16 logits [M x OP_] -> fp32 out [M x O_]
// ---------------------------------------------------------------------------
__global__ __launch_bounds__(256) void logsoftmax_kernel(
    const unsigned short* __restrict__ lg, float* __restrict__ out)
{
    const int row = blockIdx.x;
    const unsigned short* p = lg + (size_t)row * OP_;
    float* po = out + (size_t)row * O_;
    const int tid = threadIdx.x;

    float v[8];
    float mx = -1e30f;
    #pragma unroll
    for (int j = 0; j < 8; j++) {
        int col = tid + j * 256;
        v[j] = (col < O_) ? b2f(p[col]) : -1e30f;
        mx = fmaxf(mx, v[j]);
    }
    #pragma unroll
    for (int o = 32; o > 0; o >>= 1) mx = fmaxf(mx, __shfl_down(mx, o));
    __shared__ float smax[4];
    __shared__ float ssum[4];
    const int lane = tid & 63, wid = tid >> 6;
    if (lane == 0) smax[wid] = mx;
    __syncthreads();
    mx = fmaxf(fmaxf(smax[0], smax[1]), fmaxf(smax[2], smax[3]));

    float s = 0.f;
    #pragma unroll
    for (int j = 0; j < 8; j++) {
        int col = tid + j * 256;
        if (col < O_) s += expf(v[j] - mx);
    }
    #pragma unroll
    for (int o = 32; o > 0; o >>= 1) s += __shfl_down(s, o);
    if (lane == 0) ssum[wid] = s;
    __syncthreads();
    s = ssum[0] + ssum[1] + ssum[2] + ssum[3];
    const float lse = mx + logf(s);

    #pragma unroll
    for (int j = 0; j < 8; j++) {
        int col = tid + j * 256;
        if (col < O_) po[col] = v[j] - lse;
    }
}

// ---------------------------------------------------------------------------
extern "C" void kernel_launch(void* const* d_in, const int* in_sizes, int n_in,
                              void* d_out, int out_size, void* d_ws, size_t ws_size,
                              hipStream_t stream)
{
    (void)in_sizes; (void)n_in; (void)out_size; (void)ws_size;

    const float* xs    = (const float*)d_in[0];
    const float* w0    = (const float*)d_in[1];
    const float* wr    = (const float*)d_in[2];
    const float* bnz_g = (const float*)d_in[3];
    const float* bnz_b = (const float*)d_in[4];
    const float* bnz_m = (const float*)d_in[5];
    const float* bnz_v = (const float*)d_in[6];
    const float* bnc_g = (const float*)d_in[7];
    const float* bnc_b = (const float*)d_in[8];
    const float* bnc_m = (const float*)d_in[9];
    const float* bnc_v = (const float*)d_in[10];
    const float* wf    = (const float*)d_in[11];
    const float* bnf_g = (const float*)d_in[12];
    const float* bnf_b = (const float*)d_in[13];
    const float* bnf_m = (const float*)d_in[14];
    const float* bnf_v = (const float*)d_in[15];
    float* out = (float*)d_out;

    unsigned short* p = (unsigned short*)d_ws;
    unsigned short* xbuf  = p;  p += (size_t)M_ * H_;
    unsigned short* x0buf = p;  p += (size_t)M_ * DP_;
    unsigned short* zbuf  = p;  p += (size_t)M_ * H_;
    unsigned short* cbuf  = p;  p += (size_t)M_ * H_;
    unsigned short* w0p   = p;  p += (size_t)(2 * H_) * DP_;
    unsigned short* wrp   = p;  p += (size_t)(L_ - 1) * (2 * H_) * H_;
    unsigned short* wfp   = p;  p += (size_t)OP_ * H_;
    unsigned short* lbuf  = p;  p += (size_t)M_ * OP_;
    float* fp = (float*)p;
    float* zs = fp;  fp += L_ * H_;
    float* zb = fp;  fp += L_ * H_;
    float* cs = fp;  fp += L_ * H_;
    float* cb = fp;  fp += L_ * H_;
    float* fs = fp;  fp += OP_;
    float* fb = fp;  fp += OP_;
    float* sH0 = fp; fp += NC_ * B_ * H_;
    float* sP  = fp;

    dim3 blk(256);
    bn_prep<<<(L_ * H_ + 255) / 256, blk, 0, stream>>>(bnz_g, bnz_b, bnz_m, bnz_v, zs, zb, L_ * H_, L_ * H_);
    bn_prep<<<(L_ * H_ + 255) / 256, blk, 0, stream>>>(bnc_g, bnc_b, bnc_m, bnc_v, cs, cb, L_ * H_, L_ * H_);
    bn_prep<<<(OP_ + 255) / 256, blk, 0, stream>>>(bnf_g, bnf_b, bnf_m, bnf_v, fs, fb, O_, OP_);

    {
        int t0 = M_ * DP_;
        cvt_pad<<<(t0 + 255) / 256, blk, 0, stream>>>(xs, x0buf, M_, D_, DP_, t0);
        int t1 = 2 * H_ * DP_;
        cvt_pad<<<(t1 + 255) / 256, blk, 0, stream>>>(w0, w0p, 2 * H_, D_, DP_, t1);
        int t2 = (L_ - 1) * 2 * H_ * H_;
        cvt_pad<<<(t2 + 255) / 256, blk, 0, stream>>>(wr, wrp, (L_ - 1) * 2 * H_, H_, H_, t2);
        int t3 = OP_ * H_;
        cvt_pad<<<(t3 + 255) / 256, blk, 0, stream>>>(wf, wfp, O_, H_, H_, t3);
    }

    dim3 sgrid((B_ * H_) / 256, NC_);
    for (int layer = 0; layer < L_; ++layer) {
        const unsigned short* Ain = (layer == 0) ? x0buf : xbuf;
        const unsigned short* W   = (layer == 0) ? w0p : (wrp + (size_t)(layer - 1) * (2 * H_) * H_);
        const int K               = (layer == 0) ? DP_ : H_;
        dim3 grid((2 * H_) / BN, M_ / BM);
        gemm_bf16<<<grid, blk, 0, stream>>>(Ain, W, K, 0,
            zbuf, cbuf,
            zs + layer * H_, zb + layer * H_, cs + layer * H_, cb + layer * H_,
            nullptr, nullptr, nullptr);
        scan_pass1<<<sgrid, blk, 0, stream>>>(zbuf, cbuf, sH0, sP);
        scan_pass2<<<sgrid, blk, 0, stream>>>(zbuf, cbuf, sH0, sP, xbuf);
    }

    dim3 gridf(OP_ / BN, M_ / BM);
    gemm_bf16<<<gridf, blk, 0, stream>>>(xbuf, wfp, H_, 1,
        nullptr, nullptr, nullptr, nullptr, nullptr, nullptr,
        lbuf, fs, fb);

    logsoftmax_kernel<<<M_, blk, 0, stream>>>(lbuf, out);
}

// Round 4
// 1238.441 us; speedup vs baseline: 16.5875x; 1.0727x over previous
//
#include <hip/hip_runtime.h>
#include <math.h>
#include <stdint.h>

#define T_ 800
#define B_ 32
#define D_ 440
#define DP_ 448      // D padded to mult of 32
#define H_ 1024
#define L_ 4
#define O_ 2000
#define OP_ 2048     // O padded to mult of 128
#define EPS_ 1e-5f
#define M_ (T_ * B_)   // 25600
#define BH_ (B_ * H_)  // 32768
#define NC_ 16
#define TC_ (T_ / NC_) // 50

#define BM 128
#define BN 128
#define BK 32

typedef __attribute__((ext_vector_type(8))) short bf16x8;
typedef __attribute__((ext_vector_type(4))) float f32x4;

__device__ inline float b2f(unsigned short u) {
    union { unsigned int i; float f; } v; v.i = ((unsigned int)u) << 16; return v.f;
}
__device__ inline unsigned short f2b(float f) {   // RNE bf16 (finite only)
    unsigned int x = __float_as_uint(f);
    return (unsigned short)((x + 0x7FFFu + ((x >> 16) & 1u)) >> 16);
}

// ---------------------------------------------------------------------------
// BN fold with dst padding: y = x*scale + bias; i >= nsrc -> 0
// ---------------------------------------------------------------------------
__global__ void bn_prep(const float* __restrict__ g, const float* __restrict__ b,
                        const float* __restrict__ m, const float* __restrict__ v,
                        float* __restrict__ scale, float* __restrict__ bias,
                        int nsrc, int ndst)
{
    int i = blockIdx.x * 256 + threadIdx.x;
    if (i >= ndst) return;
    if (i < nsrc) {
        float s = g[i] * rsqrtf(v[i] + EPS_);
        scale[i] = s;
        bias[i] = fmaf(-m[i], s, b[i]);
    } else {
        scale[i] = 0.f;
        bias[i] = 0.f;
    }
}

// ---------------------------------------------------------------------------
// fp32 [Rs x Cs] -> bf16 [Rd x Cd], 8 cols per thread.
// Requires Cs%8==0, Cd%8==0, 16B-aligned rows.  r>=Rs or c>=Cs -> 0.
// ---------------------------------------------------------------------------
__global__ void cvt_pad8(const float* __restrict__ src, unsigned short* __restrict__ dst,
                         int Rs, int Cs, int Cd, int total8)
{
    int i = blockIdx.x * 256 + threadIdx.x;
    if (i >= total8) return;
    const int c8 = Cd >> 3;
    int r = i / c8, c = (i - r * c8) << 3;
    ushort4 lo, hi;
    if (r < Rs && c < Cs) {
        const float4 a = *(const float4*)(src + (size_t)r * Cs + c);
        const float4 b = *(const float4*)(src + (size_t)r * Cs + c + 4);
        lo = make_ushort4(f2b(a.x), f2b(a.y), f2b(a.z), f2b(a.w));
        hi = make_ushort4(f2b(b.x), f2b(b.y), f2b(b.z), f2b(b.w));
    } else {
        lo = make_ushort4(0, 0, 0, 0);
        hi = make_ushort4(0, 0, 0, 0);
    }
    unsigned short* d = dst + (size_t)r * Cd + c;
    *(ushort4*)d = lo;
    *(ushort4*)(d + 4) = hi;
}

// ---------------------------------------------------------------------------
// bf16 NT GEMM, 128x128x32 tiles, DOUBLE-BUFFERED LDS with early prefetch:
// stage(k+1) is issued before compute(k), so the vmcnt(0) drain at the next
// barrier waits on loads that already had the whole compute phase in flight.
// B tiles column-interleaved (slot s -> global row n0+(s>>6)*64+(s&15)*4+((s>>4)&3))
// so one lane's 4 ni-values are 4 consecutive columns -> ushort4 stores.
// mode 0: n<H -> z=sigmoid(bn), else c=relu(bn); bf16 [M x H]
// mode 1: logits bf16 [M x OP_], bn affine only
// ---------------------------------------------------------------------------
__global__ __launch_bounds__(256) void gemm_bf16(
    const unsigned short* __restrict__ A, const unsigned short* __restrict__ Wt,
    int K, int mode,
    unsigned short* __restrict__ zout, unsigned short* __restrict__ cout,
    const float* __restrict__ zscale, const float* __restrict__ zbias,
    const float* __restrict__ cscale, const float* __restrict__ cbias,
    unsigned short* __restrict__ fout,
    const float* __restrict__ fscale, const float* __restrict__ fbias)
{
    __shared__ unsigned short As[2][BM * BK];   // 2 x 8 KB
    __shared__ unsigned short Bs[2][BN * BK];   // 2 x 8 KB

    const int tid = threadIdx.x;
    const int lane = tid & 63;
    const int wid = tid >> 6;            // 0..3
    const int wm = wid >> 1, wn = wid & 1;
    const int m0 = blockIdx.y * BM;
    const int n0 = blockIdx.x * BN;

    const int srow = lane >> 2;
    const int scol = (lane & 3) * 8;     // element offset within row

    const int ca0 = wid * 2, ca1 = wid * 2 + 1;
    const unsigned short* aR0 = A + (size_t)(m0 + ca0 * 16 + srow) * K + scol;
    const unsigned short* aR1 = A + (size_t)(m0 + ca1 * 16 + srow) * K + scol;
    const int gn0 = n0 + ((ca0 >> 2) << 6) + srow * 4 + (ca0 & 3);
    const int gn1 = n0 + ((ca1 >> 2) << 6) + srow * 4 + (ca1 & 3);
    const unsigned short* bR0 = Wt + (size_t)gn0 * K + scol;
    const unsigned short* bR1 = Wt + (size_t)gn1 * K + scol;
    const int lofsA0 = ca0 * 16 * BK;
    const int lofsA1 = ca1 * 16 * BK;

    f32x4 acc[4][4];
    #pragma unroll
    for (int i = 0; i < 4; i++)
        #pragma unroll
        for (int j = 0; j < 4; j++)
            acc[i][j] = (f32x4){0.f, 0.f, 0.f, 0.f};

    const int fr = lane & 15;            // fragment row
    const int fk = (lane >> 4) * 8;      // fragment k offset

    const int nIters = K / BK;

    // prologue: stage k-tile 0 into buffer 0
    {
        __builtin_amdgcn_global_load_lds(
            (const __attribute__((address_space(1))) unsigned int*)aR0,
            (__attribute__((address_space(3))) unsigned int*)(As[0] + lofsA0), 16, 0, 0);
        __builtin_amdgcn_global_load_lds(
            (const __attribute__((address_space(1))) unsigned int*)aR1,
            (__attribute__((address_space(3))) unsigned int*)(As[0] + lofsA1), 16, 0, 0);
        __builtin_amdgcn_global_load_lds(
            (const __attribute__((address_space(1))) unsigned int*)bR0,
            (__attribute__((address_space(3))) unsigned int*)(Bs[0] + lofsA0), 16, 0, 0);
        __builtin_amdgcn_global_load_lds(
            (const __attribute__((address_space(1))) unsigned int*)bR1,
            (__attribute__((address_space(3))) unsigned int*)(Bs[0] + lofsA1), 16, 0, 0);
    }

    for (int it = 0; it < nIters; ++it) {
        __syncthreads();   // drains vmcnt -> buffer it&1 is ready; prior reads done

        // early prefetch of next k-tile into the other buffer
        if (it + 1 < nIters) {
            const int nk = (it + 1) * BK;
            const int nb = (it + 1) & 1;
            __builtin_amdgcn_global_load_lds(
                (const __attribute__((address_space(1))) unsigned int*)(aR0 + nk),
                (__attribute__((address_space(3))) unsigned int*)(As[nb] + lofsA0), 16, 0, 0);
            __builtin_amdgcn_global_load_lds(
                (const __attribute__((address_space(1))) unsigned int*)(aR1 + nk),
                (__attribute__((address_space(3))) unsigned int*)(As[nb] + lofsA1), 16, 0, 0);
            __builtin_amdgcn_global_load_lds(
                (const __attribute__((address_space(1))) unsigned int*)(bR0 + nk),
                (__attribute__((address_space(3))) unsigned int*)(Bs[nb] + lofsA0), 16, 0, 0);
            __builtin_amdgcn_global_load_lds(
                (const __attribute__((address_space(1))) unsigned int*)(bR1 + nk),
                (__attribute__((address_space(3))) unsigned int*)(Bs[nb] + lofsA1), 16, 0, 0);
        }

        const unsigned short* curA = As[it & 1];
        const unsigned short* curB = Bs[it & 1];
        bf16x8 af[4], bfr[4];
        #pragma unroll
        for (int t = 0; t < 4; t++) {
            af[t]  = *(const bf16x8*)(curA + (wm * 64 + t * 16 + fr) * BK + fk);
            bfr[t] = *(const bf16x8*)(curB + (wn * 64 + t * 16 + fr) * BK + fk);
        }
        #pragma unroll
        for (int mi = 0; mi < 4; mi++)
            #pragma unroll
            for (int ni = 0; ni < 4; ni++)
                acc[mi][ni] = __builtin_amdgcn_mfma_f32_16x16x32_bf16(af[mi], bfr[ni], acc[mi][ni], 0, 0, 0);
    }

    // ---- epilogue ----
    const int q = lane >> 4;
    const int colb = n0 + wn * 64 + (lane & 15) * 4;   // 4 consecutive global cols
    const int rbase = m0 + wm * 64 + q * 4;

    if (mode == 0) {
        const bool isz = (n0 < H_);
        const float* sc = isz ? zscale : cscale;
        const float* bi = isz ? zbias : cbias;
        unsigned short* dst = isz ? zout : cout;
        const int npb = isz ? colb : colb - H_;
        const float4 s4 = *(const float4*)(sc + npb);
        const float4 b4 = *(const float4*)(bi + npb);
        #pragma unroll
        for (int mi = 0; mi < 4; mi++)
            #pragma unroll
            for (int r = 0; r < 4; r++) {
                const int m = rbase + mi * 16 + r;
                float v0 = fmaf(acc[mi][0][r], s4.x, b4.x);
                float v1 = fmaf(acc[mi][1][r], s4.y, b4.y);
                float v2 = fmaf(acc[mi][2][r], s4.z, b4.z);
                float v3 = fmaf(acc[mi][3][r], s4.w, b4.w);
                if (isz) {
                    v0 = __builtin_amdgcn_rcpf(1.f + __expf(-v0));
                    v1 = __builtin_amdgcn_rcpf(1.f + __expf(-v1));
                    v2 = __builtin_amdgcn_rcpf(1.f + __expf(-v2));
                    v3 = __builtin_amdgcn_rcpf(1.f + __expf(-v3));
                } else {
                    v0 = fmaxf(v0, 0.f); v1 = fmaxf(v1, 0.f);
                    v2 = fmaxf(v2, 0.f); v3 = fmaxf(v3, 0.f);
                }
                ushort4 pk = make_ushort4(f2b(v0), f2b(v1), f2b(v2), f2b(v3));
                *(ushort4*)(dst + (size_t)m * H_ + npb) = pk;
            }
    } else {
        const float4 s4 = *(const float4*)(fscale + colb);
        const float4 b4 = *(const float4*)(fbias + colb);
        #pragma unroll
        for (int mi = 0; mi < 4; mi++)
            #pragma unroll
            for (int r = 0; r < 4; r++) {
                const int m = rbase + mi * 16 + r;
                ushort4 pk = make_ushort4(
                    f2b(fmaf(acc[mi][0][r], s4.x, b4.x)),
                    f2b(fmaf(acc[mi][1][r], s4.y, b4.y)),
                    f2b(fmaf(acc[mi][2][r], s4.z, b4.z)),
                    f2b(fmaf(acc[mi][3][r], s4.w, b4.w)));
                *(ushort4*)(fout + (size_t)m * OP_ + colb) = pk;
            }
    }
}

// ---------------------------------------------------------------------------
// Scan pass 1: per-chunk (H0, P), h_in = 0.  2 h's per thread (4B loads).
// Launched with gridDim.y = NC_-1 (last chunk's state is never consumed).
// ---------------------------------------------------------------------------
__global__ __launch_bounds__(256) void scan_pass1(
    const unsigned short* __restrict__ z, const unsigned short* __restrict__ c,
    float* __restrict__ H0, float* __restrict__ P)
{
    const int k = blockIdx.y;
    const int e2 = blockIdx.x * 256 + threadIdx.x;   // pair index < BH_/2
    float h0 = 0.f, h1 = 0.f, p0 = 1.f, p1 = 1.f;
    size_t off = ((size_t)k * TC_ * BH_ + 2 * e2) >> 1;   // in uint units
    const unsigned int* z32 = (const unsigned int*)z;
    const unsigned int* c32 = (const unsigned int*)c;
    #pragma unroll 5
    for (int t = 0; t < TC_; ++t) {
        unsigned int zz = z32[off], cc = c32[off];
        float z0 = b2f((unsigned short)zz), z1 = b2f((unsigned short)(zz >> 16));
        float c0 = b2f((unsigned short)cc), c1 = b2f((unsigned short)(cc >> 16));
        h0 = fmaf(z0, h0 - c0, c0);  p0 *= z0;
        h1 = fmaf(z1, h1 - c1, c1);  p1 *= z1;
        off += BH_ / 2;
    }
    *(float2*)(H0 + (size_t)k * BH_ + 2 * e2) = make_float2(h0, h1);
    *(float2*)(P  + (size_t)k * BH_ + 2 * e2) = make_float2(p0, p1);
}

// ---------------------------------------------------------------------------
// Scan pass 2: fold prior chunk states (exact affine composition), rerun, write x.
// ---------------------------------------------------------------------------
__global__ __launch_bounds__(256) void scan_pass2(
    const unsigned short* __restrict__ z, const unsigned short* __restrict__ c,
    const float* __restrict__ H0, const float* __restrict__ P,
    unsigned short* __restrict__ x)
{
    const int k = blockIdx.y;
    const int e2 = blockIdx.x * 256 + threadIdx.x;
    float h0 = 0.f, h1 = 0.f;
    for (int j = 0; j < k; ++j) {     // k block-uniform: no divergence
        float2 pj = *(const float2*)(P  + (size_t)j * BH_ + 2 * e2);
        float2 hj = *(const float2*)(H0 + (size_t)j * BH_ + 2 * e2);
        h0 = fmaf(pj.x, h0, hj.x);
        h1 = fmaf(pj.y, h1, hj.y);
    }
    size_t off = ((size_t)k * TC_ * BH_ + 2 * e2) >> 1;
    const unsigned int* z32 = (const unsigned int*)z;
    const unsigned int* c32 = (const unsigned int*)c;
    unsigned int* x32 = (unsigned int*)x;
    #pragma unroll 5
    for (int t = 0; t < TC_; ++t) {
        unsigned int zz = z32[off], cc = c32[off];
        float z0 = b2f((unsigned short)zz), z1 = b2f((unsigned short)(zz >> 16));
        float c0 = b2f((unsigned short)cc), c1 = b2f((unsigned short)(cc >> 16));
        h0 = fmaf(z0, h0 - c0, c0);
        h1 = fmaf(z1, h1 - c1, c1);
        x32[off] = (unsigned int)f2b(h0) | ((unsigned int)f2b(h1) << 16);
        off += BH_ / 2;
    }
}

// ---------------------------------------------------------------------------
// row-wise log_softmax: bf16 logits [M x OP_] -> fp32 out [M x O_]
// ---------------------------------------------------------------------------
__global__ __launch_bounds__(256) void logsoftmax_kernel(
    const unsigned short* __restrict__ lg, float* __restrict__ out)
{
    const int row = blockIdx.x;
    const unsigned short* p = lg + (size_t)row * OP_;
    float* po = out + (size_t)row * O_;
    const int tid = threadIdx.x;

    float v[8];
    float mx = -1e30f;
    #pragma unroll
    for (int j = 0; j < 8; j++) {
        int col = tid + j * 256;
        v[j] = (col < O_) ? b2f(p[col]) : -1e30f;
        mx = fmaxf(mx, v[j]);
    }
    #pragma unroll
    for (int o = 32; o > 0; o >>= 1) mx = fmaxf(mx, __shfl_down(mx, o));
    __shared__ float smax[4];
    __shared__ float ssum[4];
    const int lane = tid & 63, wid = tid >> 6;
    if (lane == 0) smax[wid] = mx;
    __syncthreads();
    mx = fmaxf(fmaxf(smax[0], smax[1]), fmaxf(smax[2], smax[3]));

    float s = 0.f;
    #pragma unroll
    for (int j = 0; j < 8; j++) {
        int col = tid + j * 256;
        if (col < O_) s += expf(v[j] - mx);
    }
    #pragma unroll
    for (int o = 32; o > 0; o >>= 1) s += __shfl_down(s, o);
    if (lane == 0) ssum[wid] = s;
    __syncthreads();
    s = ssum[0] + ssum[1] + ssum[2] + ssum[3];
    const float lse = mx + logf(s);

    #pragma unroll
    for (int j = 0; j < 8; j++) {
        int col = tid + j * 256;
        if (col < O_) po[col] = v[j] - lse;
    }
}

// ---------------------------------------------------------------------------
extern "C" void kernel_launch(void* const* d_in, const int* in_sizes, int n_in,
                              void* d_out, int out_size, void* d_ws, size_t ws_size,
                              hipStream_t stream)
{
    (void)in_sizes; (void)n_in; (void)out_size; (void)ws_size;

    const float* xs    = (const float*)d_in[0];
    const float* w0    = (const float*)d_in[1];
    const float* wr    = (const float*)d_in[2];
    const float* bnz_g = (const float*)d_in[3];
    const float* bnz_b = (const float*)d_in[4];
    const float* bnz_m = (const float*)d_in[5];
    const float* bnz_v = (const float*)d_in[6];
    const float* bnc_g = (const float*)d_in[7];
    const float* bnc_b = (const float*)d_in[8];
    const float* bnc_m = (const float*)d_in[9];
    const float* bnc_v = (const float*)d_in[10];
    const float* wf    = (const float*)d_in[11];
    const float* bnf_g = (const float*)d_in[12];
    const float* bnf_b = (const float*)d_in[13];
    const float* bnf_m = (const float*)d_in[14];
    const float* bnf_v = (const float*)d_in[15];
    float* out = (float*)d_out;

    unsigned short* p = (unsigned short*)d_ws;
    unsigned short* xbuf  = p;  p += (size_t)M_ * H_;
    unsigned short* x0buf = p;  p += (size_t)M_ * DP_;
    unsigned short* zbuf  = p;  p += (size_t)M_ * H_;
    unsigned short* cbuf  = p;  p += (size_t)M_ * H_;
    unsigned short* w0p   = p;  p += (size_t)(2 * H_) * DP_;
    unsigned short* wrp   = p;  p += (size_t)(L_ - 1) * (2 * H_) * H_;
    unsigned short* wfp   = p;  p += (size_t)OP_ * H_;
    unsigned short* lbuf  = p;  p += (size_t)M_ * OP_;
    float* fp = (float*)p;
    float* zs = fp;  fp += L_ * H_;
    float* zb = fp;  fp += L_ * H_;
    float* cs = fp;  fp += L_ * H_;
    float* cb = fp;  fp += L_ * H_;
    float* fs = fp;  fp += OP_;
    float* fb = fp;  fp += OP_;
    float* sH0 = fp; fp += NC_ * BH_;
    float* sP  = fp;

    dim3 blk(256);
    bn_prep<<<(L_ * H_ + 255) / 256, blk, 0, stream>>>(bnz_g, bnz_b, bnz_m, bnz_v, zs, zb, L_ * H_, L_ * H_);
    bn_prep<<<(L_ * H_ + 255) / 256, blk, 0, stream>>>(bnc_g, bnc_b, bnc_m, bnc_v, cs, cb, L_ * H_, L_ * H_);
    bn_prep<<<(OP_ + 255) / 256, blk, 0, stream>>>(bnf_g, bnf_b, bnf_m, bnf_v, fs, fb, O_, OP_);

    {   // bf16 conversions with padding (all shapes satisfy Cs%8==0, 16B rows)
        int t0 = M_ * DP_ / 8;
        cvt_pad8<<<(t0 + 255) / 256, blk, 0, stream>>>(xs, x0buf, M_, D_, DP_, t0);
        int t1 = 2 * H_ * DP_ / 8;
        cvt_pad8<<<(t1 + 255) / 256, blk, 0, stream>>>(w0, w0p, 2 * H_, D_, DP_, t1);
        int t2 = (L_ - 1) * 2 * H_ * H_ / 8;
        cvt_pad8<<<(t2 + 255) / 256, blk, 0, stream>>>(wr, wrp, (L_ - 1) * 2 * H_, H_, H_, t2);
        int t3 = OP_ * H_ / 8;
        cvt_pad8<<<(t3 + 255) / 256, blk, 0, stream>>>(wf, wfp, O_, H_, H_, t3);
    }

    dim3 sgrid1(BH_ / 512, NC_ - 1);
    dim3 sgrid2(BH_ / 512, NC_);
    for (int layer = 0; layer < L_; ++layer) {
        const unsigned short* Ain = (layer == 0) ? x0buf : xbuf;
        const unsigned short* W   = (layer == 0) ? w0p : (wrp + (size_t)(layer - 1) * (2 * H_) * H_);
        const int K               = (layer == 0) ? DP_ : H_;
        dim3 grid((2 * H_) / BN, M_ / BM);
        gemm_bf16<<<grid, blk, 0, stream>>>(Ain, W, K, 0,
            zbuf, cbuf,
            zs + layer * H_, zb + layer * H_, cs + layer * H_, cb + layer * H_,
            nullptr, nullptr, nullptr);
        scan_pass1<<<sgrid1, blk, 0, stream>>>(zbuf, cbuf, sH0, sP);
        scan_pass2<<<sgrid2, blk, 0, stream>>>(zbuf, cbuf, sH0, sP, xbuf);
    }

    dim3 gridf(OP_ / BN, M_ / BM);
    gemm_bf16<<<gridf, blk, 0, stream>>>(xbuf, wfp, H_, 1,
        nullptr, nullptr, nullptr, nullptr, nullptr, nullptr,
        lbuf, fs, fb);

    logsoftmax_kernel<<<M_, blk, 0, stream>>>(lbuf, out);
}